// Round 3
// baseline (2350.244 us; speedup 1.0000x reference)
//
#include <hip/hip_runtime.h>
#include <hip/hip_bf16.h>

#define T_STEPS 20
#define NSTEP   19
#define NN      192
#define DH      64
#define DE      32

// ---------------- workspace float offsets ----------------
// Persistent-kernel layout. Cross-block data (UH/S2/ACC/GBAR) is accessed ONLY
// through relaxed agent-scope atomics (sc0|sc1 -> coherent at LLC, no L2
// flush/inv needed). Weights stay in F and are read through the (never
// invalidated, permanently hot) L2. Row-local state lives in LDS.
enum : int {
  O_UH0   = 0,                 // [N][64] float2 {U20, HW0}  (LSTM out, gcn0 in)
  O_UH1   = O_UH0  + 2*NN*DH,  // [N][64] float2 {U21, HW1}  (gcn0 out, gcn1 in)
  O_S20   = O_UH1  + 2*NN*DH,  // [N] score j-part for p=0
  O_S21   = O_S20  + NN,
  O_ACC   = O_S21  + NN,       // [19][4]: sg, sn, sp, sm
  O_GBAR  = O_ACC  + NSTEP*4,  // {arrive_cnt, release_flag} (zeroed by k_init)
  O_WIHT  = O_GBAR + 4,        // [e][G] 8192  (zeroed state region ends here)
  O_WHHT  = O_WIHT + 8192,     // [k][G] 16384
  O_BIH   = O_WHHT + 16384,    // 256 (b_ih+b_hh)
  O_WIN   = O_BIH  + 256,
  O_BIN   = O_WIN  + 64,
  O_WRELF = O_BIN  + 32,       // 128  [p][d][c]
  O_BRELF = O_WRELF+ 128,
  O_WGR   = O_BRELF+ 64,       // 4096 [p][d][h]  (transposed for coalesced reg-load)
  O_WGH1T = O_WGR  + 4096,     // 8192 [p][k][h]
  O_WGH2T = O_WGH1T+ 8192,
  O_BGATE = O_WGH2T+ 8192,     // contiguous small-const region cB starts here:
  O_WARR  = O_BGATE+ 128,      //   BGATE 128, WARR 64, WARH1 128, WARH2 128, BAR 4
  O_WARH1 = O_WARR + 64,
  O_WARH2 = O_WARH1+ 128,
  O_BAR   = O_WARH2+ 128,
  O_WNEIT = O_BAR  + 4,        // 8192 [p][k][h]
  O_WOUT  = O_WNEIT+ 8192,     // cC: WOUT 128, BOUT 2
  O_BOUT  = O_WOUT + 128,
  O_ISF   = O_BOUT + 2,        // dtype flag (written by k_init)
  O_TOTAL = O_ISF  + 1
};

typedef unsigned long long ull;

__device__ __forceinline__ float bf2f(__hip_bfloat16 v) { return __bfloat162float(v); }
__device__ __forceinline__ float sigm(float x) { return 1.0f / (1.0f + __expf(-x)); }
__device__ __forceinline__ float tanh_fast(float x) {
  float e = __expf(-2.0f * fabsf(x));
  float r = (1.0f - e) / (1.0f + e);
  return copysignf(r, x);
}

__device__ __forceinline__ float ldf(const void* p, int idx, int isf32) {
  if (isf32) return ((const float*)p)[idx];
  return bf2f(((const __hip_bfloat16*)p)[idx]);
}
__device__ __forceinline__ void stf(void* p, int idx, float v, int isf32) {
  if (isf32) ((float*)p)[idx] = v;
  else       ((__hip_bfloat16*)p)[idx] = __float2bfloat16(v);
}

// cross-block coherent accessors (LLC-level, no fences)
__device__ __forceinline__ float cohldf(const float* p) {
  return __hip_atomic_load((float*)p, __ATOMIC_RELAXED, __HIP_MEMORY_SCOPE_AGENT);
}
__device__ __forceinline__ ull cohldu(const ull* p) {
  return __hip_atomic_load((ull*)p, __ATOMIC_RELAXED, __HIP_MEMORY_SCOPE_AGENT);
}
__device__ __forceinline__ void cohstf(float* p, float v) {
  __hip_atomic_store(p, v, __ATOMIC_RELAXED, __HIP_MEMORY_SCOPE_AGENT);
}
__device__ __forceinline__ float2 ull2f2(ull v) {
  float2 r; r.x = __uint_as_float((unsigned)v);
  r.y = __uint_as_float((unsigned)(v >> 32)); return r;
}

__device__ __forceinline__ int read_isf(const float* F, int tid, int* s_isf) {
  if (tid == 0) *s_isf = (int)F[O_ISF];
  __syncthreads();
  return *s_isf;
}

// Fence-free grid barrier. 192 blocks, 1 block/CU (131KB LDS), plain launch:
// all co-resident on the 256-CU chip (proven live in round 2). No threadfence:
// cross-block data moves via sc-bypass atomics (already at LLC once vmcnt==0),
// so the barrier only needs counter+flag atomics, which are LLC-coherent.
__device__ __forceinline__ void gridbar(float* F, unsigned ep) {
  __builtin_amdgcn_s_waitcnt(0);   // per-wave: all my vmem (incl. bypass stores) done
  __syncthreads();
  if (threadIdx.x == 0) {
    unsigned* bar = (unsigned*)(F + O_GBAR);
    unsigned v = __hip_atomic_fetch_add(bar, 1u, __ATOMIC_RELAXED,
                                        __HIP_MEMORY_SCOPE_AGENT) + 1u;
    if (v == (ep + 1u) * (unsigned)NN) {
      __hip_atomic_store(bar + 1, ep + 1u, __ATOMIC_RELAXED,
                         __HIP_MEMORY_SCOPE_AGENT);
    } else {
      while (__hip_atomic_load(bar + 1, __ATOMIC_RELAXED,
                               __HIP_MEMORY_SCOPE_AGENT) < ep + 1u)
        __builtin_amdgcn_s_sleep(1);
    }
  }
  __syncthreads();
}

// ---------------- init: detect dtype, zero state, convert/transpose weights ----
__global__ __launch_bounds__(256) void k_init(float* __restrict__ F,
                       void* __restrict__ out,
                       const void* w_in,  const void* b_in,
                       const void* w_ih,  const void* w_hh,
                       const void* b_ih,  const void* b_hh,
                       const void* w_rel, const void* b_rel,
                       const void* w_gate,const void* b_gate,
                       const void* w_ar,  const void* b_ar,
                       const void* w_nei, const void* w_out,
                       const void* b_out) {
  __shared__ int s_isf;
  const int wave = threadIdx.x >> 6, lane = threadIdx.x & 63;
  // dtype detect: fp32 reinterpreted as bf16 half-words is ~49% |v|>4-or-NaN;
  // real bf16 (sigma 0.1) never is. (proven r3-r9)
  if (wave == 0) {
    const unsigned short* u = (const unsigned short*)w_gate;
    int bad = 0;
    for (int x = lane; x < 1024; x += 64) {
      float v = __uint_as_float(((unsigned)u[x]) << 16);
      if (!(fabsf(v) <= 4.0f)) bad++;
    }
    for (int o = 32; o >= 1; o >>= 1) bad += __shfl_xor(bad, o, 64);
    if (lane == 0) s_isf = (bad > 64);
  }
  __syncthreads();
  const int isf32 = s_isf;
  if (blockIdx.x == 0 && threadIdx.x == 0) F[O_ISF] = (float)isf32;

  int tid = blockIdx.x * blockDim.x + threadIdx.x;
  int stride = gridDim.x * blockDim.x;
  for (int x = tid; x < O_WIHT; x += stride) F[x] = 0.f;
  for (int x = tid; x < NN*2;  x += stride) stf(out, (T_STEPS-1)*NN*2 + x, 0.f, isf32);
  for (int x = tid; x < 8192;  x += stride) { int e = x >> 8, G = x & 255; F[O_WIHT + x] = ldf(w_ih, G*32 + e, isf32); }
  for (int x = tid; x < 16384; x += stride) { int k = x >> 8, G = x & 255; F[O_WHHT + x] = ldf(w_hh, G*64 + k, isf32); }
  for (int x = tid; x < 256;   x += stride) F[O_BIH + x] = ldf(b_ih, x, isf32) + ldf(b_hh, x, isf32);
  for (int x = tid; x < 64;    x += stride) F[O_WIN + x] = ldf(w_in, x, isf32);
  for (int x = tid; x < 32;    x += stride) F[O_BIN + x] = ldf(b_in, x, isf32);
  for (int x = tid; x < 128;   x += stride) F[O_WRELF + x] = ldf(w_rel, x, isf32);
  for (int x = tid; x < 64;    x += stride) F[O_BRELF + x] = ldf(b_rel, x, isf32);
  // WGR transposed: [p][d][h]  (coalesced per-lane register-cache loads)
  for (int x = tid; x < 4096;  x += stride) { int p = x >> 11, d = (x >> 6) & 31, h = x & 63;
    F[O_WGR + x] = ldf(w_gate, p*10240 + h*160 + d, isf32); }
  for (int x = tid; x < 8192;  x += stride) { int p = x >> 12, k = (x >> 6) & 63, h = x & 63;
    F[O_WGH1T + x] = ldf(w_gate, p*10240 + h*160 + 32 + k, isf32); }
  for (int x = tid; x < 8192;  x += stride) { int p = x >> 12, k = (x >> 6) & 63, h = x & 63;
    F[O_WGH2T + x] = ldf(w_gate, p*10240 + h*160 + 96 + k, isf32); }
  for (int x = tid; x < 128;   x += stride) F[O_BGATE + x] = ldf(b_gate, x, isf32);
  for (int x = tid; x < 64;    x += stride) { int p = x >> 5, d = x & 31; F[O_WARR + x] = ldf(w_ar, p*160 + d, isf32); }
  for (int x = tid; x < 128;   x += stride) { int p = x >> 6, k = x & 63; F[O_WARH1 + x] = ldf(w_ar, p*160 + 32 + k, isf32); }
  for (int x = tid; x < 128;   x += stride) { int p = x >> 6, k = x & 63; F[O_WARH2 + x] = ldf(w_ar, p*160 + 96 + k, isf32); }
  for (int x = tid; x < 2;     x += stride) F[O_BAR + x] = ldf(b_ar, x, isf32);
  for (int x = tid; x < 8192;  x += stride) { int p = x >> 12, k = (x >> 6) & 63, h = x & 63;
    F[O_WNEIT + x] = ldf(w_nei, p*4096 + h*64 + k, isf32); }
  for (int x = tid; x < 128;   x += stride) F[O_WOUT + x] = ldf(w_out, x, isf32);
  for (int x = tid; x < 2;     x += stride) F[O_BOUT + x] = ldf(b_out, x, isf32);
}

// LSTM step t for row i + prep for gcn p=0. LSTM weights from registers;
// gate-prep weights from (hot) L2. Publishes UH0 {U20,HW0} and S20[i] via
// bypass stores. No trailing __syncthreads (gridbar provides it).
__device__ __forceinline__ void lstm_prep(
    float* __restrict__ F, const void* __restrict__ nnorm, int isf32,
    int t, int i, int tid, int wave, int lane,
    const float* wih_r, const float* whh_r, float bih_r,
    const float* s_win, const float* s_cB,
    float* s_x, float* s_hc, float* s_cc, float* s_gates, float* s_h1,
    float* s_cw, float* s_og, float* s_u1, float* s_s1)
{
  if (wave == 1 && lane < DE) {
    float nx = ldf(nnorm, (t*NN + i)*2 + 0, isf32);
    float ny = ldf(nnorm, (t*NN + i)*2 + 1, isf32);
    s_x[lane] = fmaxf(nx*s_win[lane*2] + ny*s_win[lane*2 + 1] + s_win[64 + lane], 0.f);
  }
  __syncthreads();
  {
    float acc = bih_r;                              // gate-major G = tid
#pragma unroll
    for (int e = 0; e < DE; e++) acc += wih_r[e] * s_x[e];
#pragma unroll
    for (int k = 0; k < DH; k++) acc += whh_r[k] * s_hc[k];
    s_gates[tid] = acc;
  }
  __syncthreads();
  if (wave == 0) {
    float ig = sigm(s_gates[lane]);
    float fg = sigm(s_gates[64 + lane]);
    float gg = tanh_fast(s_gates[128 + lane]);
    float og = sigm(s_gates[192 + lane]);
    float c1 = fg * s_cc[lane] + ig * gg;
    float h1 = og * tanh_fast(c1);
    s_cw[lane] = c1;
    s_og[lane] = og;
    s_h1[lane] = h1;
    cohstf(&F[O_UH0 + 2*(i*DH + lane) + 1], h1);    // publish HW0 (.y)
  }
  __syncthreads();
  if (wave == 0) {
    float a = 0.f;
    const float* w = F + O_WGH1T + lane;            // p=0, L2-hot
#pragma unroll
    for (int k = 0; k < DH; k++) a += w[k*DH] * s_h1[k];
    s_u1[lane] = a;
  } else if (wave == 1) {
    float a = 0.f;
    const float* w = F + O_WGH2T + lane;            // p=0, L2-hot
#pragma unroll
    for (int k = 0; k < DH; k++) a += w[k*DH] * s_h1[k];
    cohstf(&F[O_UH0 + 2*(i*DH + lane)], a);         // publish U20 (.x)
  } else if (wave == 2) {
    float hp = s_h1[lane];
    float a1 = hp * s_cB[192 + lane];               // WARH1 p=0
    float a2 = hp * s_cB[320 + lane];               // WARH2 p=0
    for (int o = 32; o >= 1; o >>= 1) { a1 += __shfl_xor(a1, o, 64); a2 += __shfl_xor(a2, o, 64); }
    if (lane == 0) { *s_s1 = a1; cohstf(&F[O_S20 + i], a2); }
  }
}

// ---------------- one GCN pass (P compile-time: 0 or 1) ----------------
template<int P>
__device__ __forceinline__ void gcn_pass(
    float* __restrict__ F, const void* __restrict__ nabs,
    const void* __restrict__ nnorm,
    const int* __restrict__ seq, const int* __restrict__ nei,
    void* __restrict__ out, int t, int last, int isf32, int m_i,
    int tid, int wave, int lane, int i,
    const float* wgP_r, float bgP,
    const float* wih_r, const float* whh_r, float bih_r,
    float* s_rt, float2* s_uhm, float* s_score, float* s_pos, float* s_neif,
    int* s_jlist, float* s_red, float* s_v1, float* s_msg, float* s_hprep,
    float* s_x, float* s_hc, float* s_cc, float* s_gates, float* s_h1,
    float* s_cw, float* s_og, float* s_u1, float* s_s1, int* s_nv,
    const float* s_cA, const float* s_cB, const float* s_cC,
    const float* s_win)
{
  const int UHr = P ? O_UH1 : O_UH0;
  const int S2r = P ? O_S21 : O_S20;

  // ---- Stage A: small loads first (in-order vmcnt retirement => they
  // complete before the gather), then issue the 48-wide UH gather (bypass
  // loads straight from LLC); its latency overlaps P1 + P2.
  const int jA  = wave*64 + lane;
  const int jj  = (jA < NN) ? jA : 0;
  const int seqj = seq[t*NN + jj];
  const int neij = nei[(t*NN + i)*NN + jj];
  const float ax = ldf(nabs, (t*NN + i)*2 + 0, isf32);
  const float ay = ldf(nabs, (t*NN + i)*2 + 1, isf32);
  const float bx = ldf(nabs, (t*NN + jj)*2 + 0, isf32);
  const float by = ldf(nabs, (t*NN + jj)*2 + 1, isf32);
  const float s2j = cohldf(&F[S2r + jj]);
  __builtin_amdgcn_sched_barrier(0);
  ull gbuf[48];
  {
    const ull* UHsrc = (const ull*)(F + UHr);
#pragma unroll
    for (int q = 0; q < 48; q++)
      gbuf[q] = cohldu(UHsrc + tid + q*256);
  }
  __builtin_amdgcn_sched_barrier(0);

  // ---- P1: mask, r values, raw scores (waves 0-2)
  if (wave < 3) {
    const int j = jA;
    int nf = m_i && (seqj > 0) && (neij > 0);
    s_neif[j] = nf ? 1.f : 0.f;
    float sc = 0.f;
    if (nf) {
      float cx = ax - bx, cy = ay - by;
      const float* wr = s_cA + P*64;
      const float* br = s_cA + 128 + P*32;
      const float* wa = s_cB + 128 + P*32;             // WARR
      float dot = 0.f;
#pragma unroll
      for (int d = 0; d < 32; d++) {
        float rv = fmaxf(cx*wr[2*d] + cy*wr[2*d+1] + br[d], 0.f);
        s_rt[j*33 + d] = rv;
        dot += rv * wa[d];
      }
      sc = dot + *s_s1 + s2j + s_cB[448 + P];          // BAR
    }
    s_score[j] = sc;
  }
  __syncthreads();

  // ---- mirror write (all waves; waits remaining gather) + P2 (wave 0)
  {
    float2* dst = s_uhm;
#pragma unroll
    for (int q = 0; q < 48; q++) dst[tid + q*256] = ull2f2(gbuf[q]);
  }
  if (wave == 0) {
    float n0 = s_neif[lane], n1 = s_neif[64+lane], n2 = s_neif[128+lane];
    float sc0 = s_score[lane], sc1 = s_score[64+lane], sc2 = s_score[128+lane];
    const float NEG = -3.0e38f;
    float mx = fmaxf(fmaxf(n0 > 0.f ? sc0 : NEG, n1 > 0.f ? sc1 : NEG),
                     n2 > 0.f ? sc2 : NEG);
    for (int o = 32; o >= 1; o >>= 1) mx = fmaxf(mx, __shfl_xor(mx, o, 64));
    float e0 = (n0 > 0.f) ? __expf(sc0 - mx) : 0.f;
    float e1 = (n1 > 0.f) ? __expf(sc1 - mx) : 0.f;
    float e2 = (n2 > 0.f) ? __expf(sc2 - mx) : 0.f;
    float s = e0 + e1 + e2;
    for (int o = 32; o >= 1; o >>= 1) s += __shfl_xor(s, o, 64);
    float inv = (s > 0.f) ? 1.0f / s : 0.f;
    float p0 = e0*inv, p1 = e1*inv, p2 = e2*inv;
    s_pos[lane] = p0; s_pos[64+lane] = p1; s_pos[128+lane] = p2;
    ull m0 = __ballot(n0 > 0.f), m1 = __ballot(n1 > 0.f), m2 = __ballot(n2 > 0.f);
    ull lt = (1ull << lane) - 1ull;
    int c0 = __popcll(m0), c1 = __popcll(m1);
    if (n0 > 0.f) s_jlist[__popcll(m0 & lt)] = lane;
    if (n1 > 0.f) s_jlist[c0 + __popcll(m1 & lt)] = 64 + lane;
    if (n2 > 0.f) s_jlist[c0 + c1 + __popcll(m2 & lt)] = 128 + lane;
    if (lane == 0) *s_nv = c0 + c1 + __popcll(m2);
    if (P == 0 && m_i) {
      float cnt = n0 + n1 + n2;
      float pm  = fmaxf(fmaxf(p0, p1), p2);
      for (int o = 32; o >= 1; o >>= 1) {
        cnt += __shfl_xor(cnt, o, 64);
        pm   = fmaxf(pm, __shfl_xor(pm, o, 64));
      }
      if (lane == 0 && cnt > 0.f) {
        atomicAdd(&F[O_ACC + t*4 + 1], cnt);
        atomicAdd(&F[O_ACC + t*4 + 2], pm);
        atomicAdd(&F[O_ACC + t*4 + 3], 1.f);
      }
    }
  }
  __syncthreads();

  // ---- P3: gates + msg partials over compacted list, ALL from LDS (lane=h)
  {
    float msg = 0.f, v1 = 0.f;
    const int nv = *s_nv;
    if (m_i && nv > 0) {
      float basev = s_u1[lane] + bgP;
      for (int k = wave; k < nv; k += 4) {
        int j = s_jlist[k];
        float2 uh = s_uhm[j*DH + lane];
        float acc = basev + uh.x;
        const float* rr = &s_rt[j*33];
#pragma unroll
        for (int d = 0; d < 32; d++) acc += rr[d] * wgP_r[d];
        float g = sigm(acc);
        v1 += g;
        msg += s_pos[j] * g * uh.y;
      }
    }
    s_red[wave*DH + lane] = msg;
    for (int o = 32; o >= 1; o >>= 1) v1 += __shfl_xor(v1, o, 64);
    if (lane == 0) s_v1[wave] = v1;
  }
  __syncthreads();

  // ---- T1: combine partials + v1 atomic (wave 0)
  if (wave == 0) {
    s_msg[lane] = s_red[lane] + s_red[64+lane] + s_red[128+lane] + s_red[192+lane];
    if (P == 0 && m_i && lane == 0) {
      float v1t = s_v1[0] + s_v1[1] + s_v1[2] + s_v1[3];
      atomicAdd(&F[O_ACC + t*4 + 0], v1t);
    }
  }
  __syncthreads();

  // ---- T2: c/h update; publish (P=0) or commit-to-LDS (P=1)
  if (wave == 0) {
    float hcom, ccom = 0.f;
    if (m_i) {
      float cn = s_cw[lane];
      const float* wn = F + O_WNEIT + P*4096 + lane;   // L2-hot
#pragma unroll
      for (int k = 0; k < DH; k++) cn += s_msg[k] * wn[k*DH];
      hcom = s_og[lane] * tanh_fast(cn);
      s_cw[lane] = cn;
      ccom = cn;
    } else {
      // gcn is identity for masked rows: previous phase's own-row h
      hcom = P ? s_hprep[lane] : s_h1[lane];
    }
    if (P == 0) cohstf(&F[O_UH1 + 2*(i*DH + lane) + 1], hcom);  // publish HW1
    s_hprep[lane] = hcom;
    if (P == 1 && m_i) { s_hc[lane] = hcom; s_cc[lane] = ccom; }
  }
  __syncthreads();

  if (P == 0) {
    // ---- PREP for p=1 from post-gcn0 h
    if (wave == 0) {
      float a = 0.f;
      const float* w = F + O_WGH1T + 4096 + lane;      // p=1, L2-hot
#pragma unroll
      for (int k = 0; k < DH; k++) a += w[k*DH] * s_hprep[k];
      s_u1[lane] = a;
    } else if (wave == 1) {
      float a = 0.f;
      const float* w = F + O_WGH2T + 4096 + lane;      // p=1, L2-hot
#pragma unroll
      for (int k = 0; k < DH; k++) a += w[k*DH] * s_hprep[k];
      cohstf(&F[O_UH1 + 2*(i*DH + lane)], a);          // publish U21 (.x)
    } else if (wave == 2) {
      float hp = s_hprep[lane];
      float a1 = hp * s_cB[192 + DH + lane];           // WARH1 p=1
      float a2 = hp * s_cB[320 + DH + lane];           // WARH2 p=1
      for (int o = 32; o >= 1; o >>= 1) { a1 += __shfl_xor(a1, o, 64); a2 += __shfl_xor(a2, o, 64); }
      if (lane == 0) { *s_s1 = a1; cohstf(&F[O_S21 + i], a2); }
    }
  } else {
    // ---- OUT row for step t
    if (wave == 0 && lane < 2) {
      float a = 0.f;
      if (m_i) {
        a = s_cC[128 + lane];                          // BOUT
        const float* wo = s_cC + lane*DH;              // WOUT
#pragma unroll
        for (int h = 0; h < DH; h++) a += s_hprep[h] * wo[h];
      }
      stf(out, (t*NN + i)*2 + lane, a, isf32);
    }
    if (!last) {
      // ---- fused LSTM(t+1) + prep p=0 (s_hc/s_cc committed in T2, synced)
      lstm_prep(F, nnorm, isf32, t + 1, i, tid, wave, lane,
                wih_r, whh_r, bih_r, s_win, s_cB,
                s_x, s_hc, s_cc, s_gates, s_h1, s_cw, s_og, s_u1, s_s1);
    } else {
      // ---- finalize: own-row h/c + (block 0) scalars
      if (wave == 0) stf(out, T_STEPS*NN*2 + i*DH + lane,         s_hc[lane], isf32);
      if (wave == 1) stf(out, T_STEPS*NN*2 + NN*DH + i*DH + lane, s_cc[lane], isf32);
      if (i == 0 && tid == 0) {
        float v1 = 0.f, v2 = 0.f, v3 = 0.f;
        for (int tt = 0; tt < NSTEP; tt++) {
          float sg = cohldf(&F[O_ACC + tt*4 + 0]);
          float sn = cohldf(&F[O_ACC + tt*4 + 1]);
          float sp = cohldf(&F[O_ACC + tt*4 + 2]);
          float sm = cohldf(&F[O_ACC + tt*4 + 3]);
          v1 += sg / (sn * 64.f + 1e-6f);
          v2 += sp / (sm + 1e-6f);
          v3 += sn / 192.f;
        }
        int base = T_STEPS*NN*2 + 2*NN*DH;
        stf(out, base + 0, v1 / 20.f, isf32);
        stf(out, base + 1, v2 / 20.f, isf32);
        stf(out, base + 2, v3 / 20.f, isf32);
      }
    }
  }
}

// ---------------- persistent kernel: all 19 timesteps, 2 grid barriers/step --
__global__ __launch_bounds__(256, 1) void k_main(float* __restrict__ F,
    const void* __restrict__ nabs, const void* __restrict__ nnorm,
    const int* __restrict__ seq, const int* __restrict__ nei,
    void* __restrict__ out)
{
  // s_rt[j][33]: pad-33 -> P1 writes conflict-free, P3 reads broadcast.
  __shared__ float s_rt[NN*33];                    // 24.75 KB
  __shared__ float2 s_uhm[NN*DH];                  // 96 KB cross-block UH mirror
  __shared__ float s_score[NN], s_pos[NN], s_neif[NN];
  __shared__ int   s_jlist[NN];
  __shared__ float s_red[4*DH], s_v1[4], s_msg[DH], s_hprep[DH];
  __shared__ float s_x[DE], s_hc[DH], s_cc[DH], s_gates[4*DH], s_h1[DH];
  __shared__ float s_cw[DH], s_og[DH], s_u1[DH], s_s1;
  __shared__ float s_cA[192], s_cB[452], s_cC[130], s_win[96];
  __shared__ int   s_isf, s_nv;

  const int tid = threadIdx.x, wave = tid >> 6, lane = tid & 63;
  const int i = blockIdx.x;
  const int isf32 = read_isf(F, tid, &s_isf);

  // ---- one-time register weight caches (1 block/CU: VGPRs free to 512)
  float wih_r[DE], whh_r[DH], wg0_r[32], wg1_r[32];
  const float bih_r = F[O_BIH + tid];
#pragma unroll
  for (int e = 0; e < DE; e++) wih_r[e] = F[O_WIHT + e*256 + tid];
#pragma unroll
  for (int k = 0; k < DH; k++) whh_r[k] = F[O_WHHT + k*256 + tid];
#pragma unroll
  for (int d = 0; d < 32; d++) wg0_r[d] = F[O_WGR + d*64 + lane];
#pragma unroll
  for (int d = 0; d < 32; d++) wg1_r[d] = F[O_WGR + 2048 + d*64 + lane];
  const float bg0 = F[O_BGATE + lane], bg1 = F[O_BGATE + DH + lane];

  // ---- one-time LDS staging of small consts
  for (int x = tid; x < 192; x += 256) s_cA[x] = F[O_WRELF + x];
  for (int x = tid; x < 452; x += 256) s_cB[x] = F[O_BGATE + x];
  for (int x = tid; x < 130; x += 256) s_cC[x] = F[O_WOUT + x];
  for (int x = tid; x < 96;  x += 256) s_win[x] = F[O_WIN + x];
  if (wave == 0) { s_hc[lane] = 0.f; s_cc[lane] = 0.f; }   // t=0 state
  __syncthreads();

  lstm_prep(F, nnorm, isf32, 0, i, tid, wave, lane,
            wih_r, whh_r, bih_r, s_win, s_cB,
            s_x, s_hc, s_cc, s_gates, s_h1, s_cw, s_og, s_u1, &s_s1);

  unsigned ep = 0;
  for (int t = 0; t < NSTEP; t++) {
    const int m_i = seq[t*NN + i] > 0;
    gridbar(F, ep++);          // UH0/S20 of all rows at LLC
    gcn_pass<0>(F, nabs, nnorm, seq, nei, out, t, 0, isf32, m_i,
                tid, wave, lane, i, wg0_r, bg0, wih_r, whh_r, bih_r,
                s_rt, s_uhm, s_score, s_pos, s_neif, s_jlist,
                s_red, s_v1, s_msg, s_hprep,
                s_x, s_hc, s_cc, s_gates, s_h1,
                s_cw, s_og, s_u1, &s_s1, &s_nv,
                s_cA, s_cB, s_cC, s_win);
    gridbar(F, ep++);          // UH1/S21 of all rows at LLC
    gcn_pass<1>(F, nabs, nnorm, seq, nei, out, t, t == NSTEP - 1, isf32, m_i,
                tid, wave, lane, i, wg1_r, bg1, wih_r, whh_r, bih_r,
                s_rt, s_uhm, s_score, s_pos, s_neif, s_jlist,
                s_red, s_v1, s_msg, s_hprep,
                s_x, s_hc, s_cc, s_gates, s_h1,
                s_cw, s_og, s_u1, &s_s1, &s_nv,
                s_cA, s_cB, s_cC, s_win);
    // no barrier needed between p=1 commit and LSTM(t+1): both row-local
  }
}

extern "C" void kernel_launch(void* const* d_in, const int* in_sizes, int n_in,
                              void* d_out, int out_size, void* d_ws, size_t ws_size,
                              hipStream_t stream) {
  const void* nabs  = d_in[0];
  const void* nnorm = d_in[1];
  const int* seq = (const int*)d_in[18];
  const int* nei = (const int*)d_in[19];
  float* F = (float*)d_ws;

  k_init<<<NN, 256, 0, stream>>>(F, d_out,
      d_in[3], d_in[4], d_in[5], d_in[6], d_in[7], d_in[8], d_in[9], d_in[10],
      d_in[11], d_in[12], d_in[13], d_in[14], d_in[15], d_in[16], d_in[17]);

  k_main<<<NN, 256, 0, stream>>>(F, nabs, nnorm, seq, nei, d_out);
}

// Round 5
// 697.839 us; speedup vs baseline: 3.3679x; 3.3679x over previous
//
#include <hip/hip_runtime.h>
#include <hip/hip_bf16.h>

#define T_STEPS 20
#define NSTEP   19
#define NN      192
#define DH      64
#define DE      32

// ---------------- workspace float offsets ----------------
// UH0/UH1: interleaved float2 {u2, hw} per (row, h) — one 8B load in P3.
enum : int {
  O_H     = 0,                 // committed h   [N][64]
  O_C     = O_H    + NN*DH,
  O_UH0   = O_C    + NN*DH,    // [N][64] float2 {U20, HW0}  (LSTM out, gcn0 in)
  O_UH1   = O_UH0  + 2*NN*DH,  // [N][64] float2 {U21, HW1}  (gcn0 out, gcn1 in)
  O_CW    = O_UH1  + 2*NN*DH,  // working c
  O_OG    = O_CW   + NN*DH,    // LSTM o-gate
  O_U1    = O_OG   + NN*DH,    // h_i-part of gate preact (row-local)
  O_S1    = O_U1   + NN*DH,
  O_S20   = O_S1   + NN,
  O_S21   = O_S20  + NN,
  O_ACC   = O_S21  + NN,       // [19][4]: sg, sn, sp, sm
  O_WIHT  = O_ACC  + NSTEP*4 + 4,  // [e][G] 8192  (zeroed state region ends here)
  O_WHHT  = O_WIHT + 8192,         // [k][G] 16384
  O_BIH   = O_WHHT + 16384,        // 256 (b_ih+b_hh)
  O_WIN   = O_BIH  + 256,
  O_BIN   = O_WIN  + 64,
  O_WRELF = O_BIN  + 32,           // 128  [p][d][c]
  O_BRELF = O_WRELF+ 128,
  O_WGR   = O_BRELF+ 64,           // 4096 [p][h][d<32]
  O_WGH1T = O_WGR  + 4096,         // 8192 [p][k][h]
  O_WGH2T = O_WGH1T+ 8192,
  O_BGATE = O_WGH2T+ 8192,
  O_WARR  = O_BGATE+ 128,
  O_WARH1 = O_WARR + 64,
  O_WARH2 = O_WARH1+ 128,
  O_BAR   = O_WARH2+ 128,
  O_WNEIT = O_BAR  + 4,            // 8192 [p][k][h]
  O_WOUT  = O_WNEIT+ 8192,
  O_BOUT  = O_WOUT + 128,
  O_ISF   = O_BOUT + 2,            // dtype flag (written by k_init)
  O_TOTAL = O_ISF  + 1
};

typedef unsigned long long ull;

__device__ __forceinline__ float bf2f(__hip_bfloat16 v) { return __bfloat162float(v); }
__device__ __forceinline__ float sigm(float x) { return 1.0f / (1.0f + __expf(-x)); }
__device__ __forceinline__ float tanh_fast(float x) {
  float e = __expf(-2.0f * fabsf(x));
  float r = (1.0f - e) / (1.0f + e);
  return copysignf(r, x);
}

// dtype-flex input load / output store
__device__ __forceinline__ float ldf(const void* p, int idx, int isf32) {
  if (isf32) return ((const float*)p)[idx];
  return bf2f(((const __hip_bfloat16*)p)[idx]);
}
__device__ __forceinline__ void stf(void* p, int idx, float v, int isf32) {
  if (isf32) ((float*)p)[idx] = v;
  else       ((__hip_bfloat16*)p)[idx] = __float2bfloat16(v);
}

// resolve dtype: host hint if conclusive, else cached device flag (uniform
// address -> one broadcast load; no syncthreads needed)
__device__ __forceinline__ int resolve_isf(const float* F, int isf_arg) {
  return (isf_arg >= 0) ? isf_arg : (int)F[O_ISF];
}

// LSTM step t for row i + prep for gcn p=0. If load_hc, wave0 loads committed
// H/C from F; else caller pre-filled s_hc/s_cc (before any sync).
__device__ __forceinline__ void lstm_prep_dev(
    float* __restrict__ F, const void* __restrict__ nnorm, int isf32,
    int t, int i, int tid, int wave, int lane, int load_hc,
    float* s_x, float* s_hc, float* s_cc, float* s_gates, float* s_h1)
{
  if (load_hc && wave == 0) { s_hc[lane] = F[O_H + i*DH + lane]; s_cc[lane] = F[O_C + i*DH + lane]; }
  if (wave == 1 && lane < DE) {
    float nx = ldf(nnorm, (t*NN + i)*2 + 0, isf32);
    float ny = ldf(nnorm, (t*NN + i)*2 + 1, isf32);
    s_x[lane] = fmaxf(nx*F[O_WIN + lane*2] + ny*F[O_WIN + lane*2 + 1] + F[O_BIN + lane], 0.f);
  }
  __syncthreads();
  {
    int G = tid;                                   // gate-major: i,f,g,o
    float acc = F[O_BIH + G];
    for (int e = 0; e < DE; e++) acc += F[O_WIHT + e*256 + G] * s_x[e];
    for (int k = 0; k < DH; k++) acc += F[O_WHHT + k*256 + G] * s_hc[k];
    s_gates[G] = acc;
  }
  __syncthreads();
  if (wave == 0) {
    float ig = sigm(s_gates[lane]);
    float fg = sigm(s_gates[64 + lane]);
    float gg = tanh_fast(s_gates[128 + lane]);
    float og = sigm(s_gates[192 + lane]);
    float c1 = fg * s_cc[lane] + ig * gg;
    float h1 = og * tanh_fast(c1);
    int idx = i*DH + lane;
    F[O_CW  + idx] = c1;
    F[O_UH0 + 2*idx + 1] = h1;                     // HW0 (.y)
    F[O_OG  + idx] = og;
    s_h1[lane] = h1;
  }
  __syncthreads();
  {
    int idx = i*DH + lane;
    if (wave == 0) {
      float a = 0.f;
      const float* w = F + O_WGH1T + lane;         // p=0
      for (int k = 0; k < DH; k++) a += w[k*DH] * s_h1[k];
      F[O_U1 + idx] = a;
    } else if (wave == 1) {
      float a = 0.f;
      const float* w = F + O_WGH2T + lane;         // p=0
      for (int k = 0; k < DH; k++) a += w[k*DH] * s_h1[k];
      F[O_UH0 + 2*idx] = a;                        // U20 (.x)
    } else if (wave == 2) {
      float hp = s_h1[lane];
      float a1 = hp * F[O_WARH1 + lane];
      float a2 = hp * F[O_WARH2 + lane];
      for (int o = 32; o >= 1; o >>= 1) { a1 += __shfl_xor(a1, o, 64); a2 += __shfl_xor(a2, o, 64); }
      if (lane == 0) { F[O_S1 + i] = a1; F[O_S20 + i] = a2; }
    }
  }
}

// ---------------- init: detect dtype, zero state, convert/transpose weights ----
__global__ __launch_bounds__(256) void k_init(float* __restrict__ F,
                       void* __restrict__ out,
                       const void* w_in,  const void* b_in,
                       const void* w_ih,  const void* w_hh,
                       const void* b_ih,  const void* b_hh,
                       const void* w_rel, const void* b_rel,
                       const void* w_gate,const void* b_gate,
                       const void* w_ar,  const void* b_ar,
                       const void* w_nei, const void* w_out,
                       const void* b_out, int isf_arg) {
  __shared__ int s_isf;
  const int wave = threadIdx.x >> 6, lane = threadIdx.x & 63;
  // dtype detect (fallback when host hint inconclusive): fp32 reinterpreted
  // as bf16 half-words is ~49% |v|>4-or-NaN; real bf16 never is. (proven r3-r9)
  if (isf_arg >= 0) {
    if (threadIdx.x == 0) s_isf = isf_arg;
  } else if (wave == 0) {
    const unsigned short* u = (const unsigned short*)w_gate;
    int bad = 0;
    for (int x = lane; x < 1024; x += 64) {
      float v = __uint_as_float(((unsigned)u[x]) << 16);
      if (!(fabsf(v) <= 4.0f)) bad++;
    }
    for (int o = 32; o >= 1; o >>= 1) bad += __shfl_xor(bad, o, 64);
    if (lane == 0) s_isf = (bad > 64);
  }
  __syncthreads();
  const int isf32 = s_isf;
  if (blockIdx.x == 0 && threadIdx.x == 0) F[O_ISF] = (float)isf32;

  int tid = blockIdx.x * blockDim.x + threadIdx.x;
  int stride = gridDim.x * blockDim.x;
  for (int x = tid; x < O_WIHT; x += stride) F[x] = 0.f;
  for (int x = tid; x < NN*2;  x += stride) stf(out, (T_STEPS-1)*NN*2 + x, 0.f, isf32);
  for (int x = tid; x < 8192;  x += stride) { int e = x >> 8, G = x & 255; F[O_WIHT + x] = ldf(w_ih, G*32 + e, isf32); }
  for (int x = tid; x < 16384; x += stride) { int k = x >> 8, G = x & 255; F[O_WHHT + x] = ldf(w_hh, G*64 + k, isf32); }
  for (int x = tid; x < 256;   x += stride) F[O_BIH + x] = ldf(b_ih, x, isf32) + ldf(b_hh, x, isf32);
  for (int x = tid; x < 64;    x += stride) F[O_WIN + x] = ldf(w_in, x, isf32);
  for (int x = tid; x < 32;    x += stride) F[O_BIN + x] = ldf(b_in, x, isf32);
  for (int x = tid; x < 128;   x += stride) F[O_WRELF + x] = ldf(w_rel, x, isf32);
  for (int x = tid; x < 64;    x += stride) F[O_BRELF + x] = ldf(b_rel, x, isf32);
  for (int x = tid; x < 4096;  x += stride) { int p = x >> 11, h = (x >> 5) & 63, d = x & 31;
    F[O_WGR + x] = ldf(w_gate, p*10240 + h*160 + d, isf32); }
  for (int x = tid; x < 8192;  x += stride) { int p = x >> 12, k = (x >> 6) & 63, h = x & 63;
    F[O_WGH1T + x] = ldf(w_gate, p*10240 + h*160 + 32 + k, isf32); }
  for (int x = tid; x < 8192;  x += stride) { int p = x >> 12, k = (x >> 6) & 63, h = x & 63;
    F[O_WGH2T + x] = ldf(w_gate, p*10240 + h*160 + 96 + k, isf32); }
  for (int x = tid; x < 128;   x += stride) F[O_BGATE + x] = ldf(b_gate, x, isf32);
  for (int x = tid; x < 64;    x += stride) { int p = x >> 5, d = x & 31; F[O_WARR + x] = ldf(w_ar, p*160 + d, isf32); }
  for (int x = tid; x < 128;   x += stride) { int p = x >> 6, k = x & 63; F[O_WARH1 + x] = ldf(w_ar, p*160 + 32 + k, isf32); }
  for (int x = tid; x < 128;   x += stride) { int p = x >> 6, k = x & 63; F[O_WARH2 + x] = ldf(w_ar, p*160 + 96 + k, isf32); }
  for (int x = tid; x < 2;     x += stride) F[O_BAR + x] = ldf(b_ar, x, isf32);
  for (int x = tid; x < 8192;  x += stride) { int p = x >> 12, k = (x >> 6) & 63, h = x & 63;
    F[O_WNEIT + x] = ldf(w_nei, p*4096 + h*64 + k, isf32); }
  for (int x = tid; x < 128;   x += stride) F[O_WOUT + x] = ldf(w_out, x, isf32);
  for (int x = tid; x < 2;     x += stride) F[O_BOUT + x] = ldf(b_out, x, isf32);
}

// ---------------- LSTM t=0 + prep for gcn0 ----------------
__global__ __launch_bounds__(256) void k_lstm0(float* __restrict__ F,
                                               const void* __restrict__ nnorm,
                                               int isf_arg) {
  __shared__ float s_x[DE], s_hc[DH], s_cc[DH], s_gates[4*DH], s_h1[DH];
  const int tid = threadIdx.x, wave = tid >> 6, lane = tid & 63;
  const int isf32 = resolve_isf(F, isf_arg);
  lstm_prep_dev(F, nnorm, isf32, 0, blockIdx.x, tid, wave, lane, 1,
                s_x, s_hc, s_cc, s_gates, s_h1);
}

// ---------------- GCN pass p for step t (p==1 fuses commit/out/LSTM(t+1)/fin) --
__global__ __launch_bounds__(256) void k_gcn(float* __restrict__ F,
                                             const void* __restrict__ nabs,
                                             const void* __restrict__ nnorm,
                                             const int* __restrict__ seq,
                                             const int* __restrict__ nei,
                                             void* __restrict__ out,
                                             int t, int p, int last,
                                             int isf_arg) {
  // s_rt[j][33]: pad-33 -> P1 writes hit banks (j+d)%32 (2-way alias = free),
  // P3 reads are contiguous per j.
  __shared__ float s_rt[NN*33];                    // 24.75 KB
  __shared__ float s_score[NN], s_pos[NN], s_neif[NN];
  __shared__ int   s_jlist[NN];
  __shared__ ull   s_cmask[3];
  __shared__ float s_red[4*DH], s_v1[4], s_msg[DH], s_hprep[DH];
  __shared__ float s_x[DE], s_hc[DH], s_cc[DH], s_gates[4*DH], s_h1[DH];

  const int tid = threadIdx.x, wave = tid >> 6, lane = tid & 63;
  const int i = blockIdx.x;
  const int isf32 = resolve_isf(F, isf_arg);
  const int m_i = seq[t*NN + i] > 0;
  const int UHr = p ? O_UH1 : O_UH0;
  const int S2r = p ? O_S21 : O_S20;

  // ---- A: neighbor masks + ballot-compacted j-list (waves 0-2 in parallel).
  // Depends only on seq/nei — runs BEFORE scores so the UH gather can issue
  // early and overlap P1+P2.
  const int j = wave*64 + lane;
  ull mymask = 0; int nf = 0;
  if (wave < 3) {
    nf = m_i && (seq[t*NN + j] > 0) && (nei[(t*NN + i)*NN + j] > 0);
    s_neif[j] = nf ? 1.f : 0.f;
    mymask = __ballot(nf != 0);
    if (lane == 0) s_cmask[wave] = mymask;
  }
  __syncthreads();
  const int c0 = __popcll(s_cmask[0]), c1 = __popcll(s_cmask[1]), c2 = __popcll(s_cmask[2]);
  const int nv = c0 + c1 + c2;
  if (wave < 3 && nf) {
    int base = (wave == 0) ? 0 : (wave == 1 ? c0 : c0 + c1);
    ull lt = (1ull << lane) - 1ull;
    s_jlist[base + __popcll(mymask & lt)] = j;
  }
  __syncthreads();                                 // j-list ready

  // ---- B: issue 8-deep UH prefetch for this wave's P3 slice, then P1 scores.
  const float2* UH2 = (const float2*)(F + UHr);
  int jc[8]; float2 uc[8];
#pragma unroll
  for (int q = 0; q < 8; q++) {
    int kk = wave + q*4;
    jc[q] = (kk < nv) ? s_jlist[kk] : -1;
    uc[q] = make_float2(0.f, 0.f);
    if (jc[q] >= 0) uc[q] = UH2[jc[q]*DH + lane];
  }
  // P1: r values + raw scores (waves 0-2); UH loads in flight underneath
  if (wave < 3) {
    float sc = 0.f;
    if (nf) {
      float cx = ldf(nabs, (t*NN + i)*2 + 0, isf32) - ldf(nabs, (t*NN + j)*2 + 0, isf32);
      float cy = ldf(nabs, (t*NN + i)*2 + 1, isf32) - ldf(nabs, (t*NN + j)*2 + 1, isf32);
      const float* wr = F + O_WRELF + p*64;
      const float* br = F + O_BRELF + p*32;
      const float* wa = F + O_WARR  + p*32;
      float dot = 0.f;
#pragma unroll
      for (int d = 0; d < 32; d++) {
        float rv = fmaxf(cx*wr[2*d] + cy*wr[2*d+1] + br[d], 0.f);
        s_rt[j*33 + d] = rv;
        dot += rv * wa[d];
      }
      sc = dot + F[O_S1 + i] + F[S2r + j] + F[O_BAR + p];
    }
    s_score[j] = sc;
  }
  __syncthreads();

  // ---- C: masked softmax + (p==0) row stats (wave 0)
  if (wave == 0) {
    float n0 = s_neif[lane], n1 = s_neif[64+lane], n2 = s_neif[128+lane];
    float sc0 = s_score[lane], sc1 = s_score[64+lane], sc2 = s_score[128+lane];
    const float NEG = -3.0e38f;
    float mx = fmaxf(fmaxf(n0 > 0.f ? sc0 : NEG, n1 > 0.f ? sc1 : NEG),
                     n2 > 0.f ? sc2 : NEG);
    for (int o = 32; o >= 1; o >>= 1) mx = fmaxf(mx, __shfl_xor(mx, o, 64));
    float e0 = (n0 > 0.f) ? __expf(sc0 - mx) : 0.f;
    float e1 = (n1 > 0.f) ? __expf(sc1 - mx) : 0.f;
    float e2 = (n2 > 0.f) ? __expf(sc2 - mx) : 0.f;
    float s = e0 + e1 + e2;
    for (int o = 32; o >= 1; o >>= 1) s += __shfl_xor(s, o, 64);
    float inv = (s > 0.f) ? 1.0f / s : 0.f;
    float p0 = e0*inv, p1 = e1*inv, p2 = e2*inv;
    s_pos[lane] = p0; s_pos[64+lane] = p1; s_pos[128+lane] = p2;
    if (p == 0 && m_i) {
      float cnt = n0 + n1 + n2;
      float pm  = fmaxf(fmaxf(p0, p1), p2);
      for (int o = 32; o >= 1; o >>= 1) {
        cnt += __shfl_xor(cnt, o, 64);
        pm   = fmaxf(pm, __shfl_xor(pm, o, 64));
      }
      if (lane == 0 && cnt > 0.f) {
        atomicAdd(&F[O_ACC + t*4 + 1], cnt);
        atomicAdd(&F[O_ACC + t*4 + 2], pm);
        atomicAdd(&F[O_ACC + t*4 + 3], 1.f);
      }
    }
  }
  __syncthreads();

  // ---- P3: gates + msg partials over compacted list (lane = h).
  // 8-deep rolling prefetch, all statically indexed.
  {
    float msg = 0.f, v1 = 0.f;
    if (m_i && nv > 0) {
      float wreg[32];
      const float* wgp = F + O_WGR + p*2048 + lane*32;
#pragma unroll
      for (int d = 0; d < 32; d++) wreg[d] = wgp[d];
      float basev = F[O_U1 + i*DH + lane] + F[O_BGATE + p*DH + lane];
      for (int k = wave; k < nv; k += 32) {
        int jn[8]; float2 un[8];
#pragma unroll
        for (int q = 0; q < 8; q++) {
          int kk = k + 32 + q*4;
          jn[q] = (kk < nv) ? s_jlist[kk] : -1;
          un[q] = make_float2(0.f, 0.f);
          if (jn[q] >= 0) un[q] = UH2[jn[q]*DH + lane];
        }
#pragma unroll
        for (int q = 0; q < 8; q++) {
          if (jc[q] >= 0) {
            float acc = basev + uc[q].x;
            const float* rr = &s_rt[jc[q]*33];
#pragma unroll
            for (int d = 0; d < 32; d++) acc += rr[d] * wreg[d];
            float g = sigm(acc);
            v1 += g;
            msg += s_pos[jc[q]] * g * uc[q].y;
          }
        }
#pragma unroll
        for (int q = 0; q < 8; q++) { jc[q] = jn[q]; uc[q] = un[q]; }
      }
    }
    s_red[wave*DH + lane] = msg;
    for (int o = 32; o >= 1; o >>= 1) v1 += __shfl_xor(v1, o, 64);
    if (lane == 0) s_v1[wave] = v1;
  }
  __syncthreads();

  // ---- T1: combine partials + v1 atomic (wave 0)
  if (wave == 0) {
    s_msg[lane] = s_red[lane] + s_red[64+lane] + s_red[128+lane] + s_red[192+lane];
    if (p == 0 && m_i && lane == 0) {
      float v1t = s_v1[0] + s_v1[1] + s_v1[2] + s_v1[3];
      atomicAdd(&F[O_ACC + t*4 + 0], v1t);
    }
  }
  __syncthreads();

  // ---- T2: c/h update; publish (p=0) or commit (p=1)
  if (wave == 0) {
    int idx = i*DH + lane;
    float hcom, ccom = 0.f;
    if (m_i) {
      float cn = F[O_CW + idx];
      const float* wn = F + O_WNEIT + p*4096 + lane;
      for (int k = 0; k < DH; k++) cn += s_msg[k] * wn[k*DH];
      hcom = F[O_OG + idx] * tanh_fast(cn);
      F[O_CW + idx] = cn;
      ccom = cn;
      if (p == 1) { F[O_H + idx] = hcom; F[O_C + idx] = ccom; }
    } else {
      hcom = F[UHr + 2*idx + 1];             // gcn is identity for masked rows
    }
    if (p == 0) F[O_UH1 + 2*idx + 1] = hcom; // publish HW1 (.y), all rows
    s_hprep[lane] = hcom;
    if (p == 1) {                            // committed state for LSTM / final
      s_hc[lane] = m_i ? hcom : F[O_H + idx];
      s_cc[lane] = m_i ? ccom : F[O_C + idx];
    }
  }
  __syncthreads();

  if (p == 0) {
    // ---- PREP for p=1 from post-gcn0 h
    int idx = i*DH + lane;
    if (wave == 0) {
      float a = 0.f;
      const float* w = F + O_WGH1T + 4096 + lane;   // p=1
      for (int k = 0; k < DH; k++) a += w[k*DH] * s_hprep[k];
      F[O_U1 + idx] = a;
    } else if (wave == 1) {
      float a = 0.f;
      const float* w = F + O_WGH2T + 4096 + lane;   // p=1
      for (int k = 0; k < DH; k++) a += w[k*DH] * s_hprep[k];
      F[O_UH1 + 2*idx] = a;                         // U21 (.x), all rows
    } else if (wave == 2) {
      float hp = s_hprep[lane];
      float a1 = hp * F[O_WARH1 + DH + lane];       // p=1
      float a2 = hp * F[O_WARH2 + DH + lane];
      for (int o = 32; o >= 1; o >>= 1) { a1 += __shfl_xor(a1, o, 64); a2 += __shfl_xor(a2, o, 64); }
      if (lane == 0) { F[O_S1 + i] = a1; F[O_S21 + i] = a2; }
    }
  } else {
    // ---- OUT row for step t
    if (wave == 0 && lane < 2) {
      float a = 0.f;
      if (m_i) {
        a = F[O_BOUT + lane];
        const float* wo = F + O_WOUT + lane*DH;
        for (int h = 0; h < DH; h++) a += s_hprep[h] * wo[h];
      }
      stf(out, (t*NN + i)*2 + lane, a, isf32);
    }
    if (!last) {
      // ---- fused LSTM(t+1) + prep p=0 (s_hc/s_cc set in T2, synced above)
      lstm_prep_dev(F, nnorm, isf32, t + 1, i, tid, wave, lane, 0,
                    s_x, s_hc, s_cc, s_gates, s_h1);
    } else {
      // ---- finalize: own-row h/c + (block 0) scalars
      if (wave == 0) stf(out, T_STEPS*NN*2 + i*DH + lane,         s_hc[lane], isf32);
      if (wave == 1) stf(out, T_STEPS*NN*2 + NN*DH + i*DH + lane, s_cc[lane], isf32);
      if (i == 0 && tid == 0) {
        float v1 = 0.f, v2 = 0.f, v3 = 0.f;
        for (int tt = 0; tt < NSTEP; tt++) {
          float sg = F[O_ACC + tt*4 + 0], sn = F[O_ACC + tt*4 + 1];
          float sp = F[O_ACC + tt*4 + 2], sm = F[O_ACC + tt*4 + 3];
          v1 += sg / (sn * 64.f + 1e-6f);
          v2 += sp / (sm + 1e-6f);
          v3 += sn / 192.f;
        }
        int base = T_STEPS*NN*2 + 2*NN*DH;
        stf(out, base + 0, v1 / 20.f, isf32);
        stf(out, base + 1, v2 / 20.f, isf32);
        stf(out, base + 2, v3 / 20.f, isf32);
      }
    }
  }
}

extern "C" void kernel_launch(void* const* d_in, const int* in_sizes, int n_in,
                              void* d_out, int out_size, void* d_ws, size_t ws_size,
                              hipStream_t stream) {
  const void* nabs  = d_in[0];
  const void* nnorm = d_in[1];
  const int* seq = (const int*)d_in[18];
  const int* nei = (const int*)d_in[19];
  float* F = (float*)d_ws;

  // host-side dtype hint from w_gate byte size (2*64*160 elements):
  // 81920 B -> fp32, 40960 B -> bf16; anything else -> -1 (device detect).
  int isf = -1;
  if (n_in > 11 && in_sizes) {
    if      (in_sizes[11] == 81920) isf = 1;
    else if (in_sizes[11] == 40960) isf = 0;
  }

  k_init<<<NN, 256, 0, stream>>>(F, d_out,
      d_in[3], d_in[4], d_in[5], d_in[6], d_in[7], d_in[8], d_in[9], d_in[10],
      d_in[11], d_in[12], d_in[13], d_in[14], d_in[15], d_in[16], d_in[17], isf);
  k_lstm0<<<NN, 256, 0, stream>>>(F, nnorm, isf);
  for (int t = 0; t < NSTEP; t++) {
    k_gcn<<<NN, 256, 0, stream>>>(F, nabs, nnorm, seq, nei, d_out, t, 0, 0, isf);
    k_gcn<<<NN, 256, 0, stream>>>(F, nabs, nnorm, seq, nei, d_out, t, 1, t == NSTEP - 1, isf);
  }
}